// Round 6
// baseline (713.245 us; speedup 1.0000x reference)
//
#include <hip/hip_runtime.h>
#include <hip/hip_bf16.h>
#include <hip/hip_fp16.h>
#include <math.h>

#define NHID 128
#define NCLASS 40
#define NBLK 256          // edge-chunk blocks for bucket passes
#define MAXBUK 1600       // >= ceil(N/64)

typedef _Float16 f16;
typedef f16 f16x8 __attribute__((ext_vector_type(8)));
typedef float f32x4 __attribute__((ext_vector_type(4)));

// ---------------- CSR build: 2-level counting sort (LDS atomics only) ----
// eb entries packed: (src << 6) | (dst & 63)  [src < 2^17, fits easily]

__global__ __launch_bounds__(256) void bucket_hist(const int* __restrict__ dst,
                                                   int* __restrict__ bh,
                                                   int E, int nbuk, int chunk) {
    __shared__ int h[MAXBUK];
    for (int i = threadIdx.x; i < nbuk; i += 256) h[i] = 0;
    __syncthreads();
    int b = blockIdx.x;
    int lo = b * chunk, hi = min(E, lo + chunk);
    for (int e = lo + threadIdx.x; e < hi; e += 256) atomicAdd(&h[dst[e] >> 6], 1);
    __syncthreads();
    for (int i = threadIdx.x; i < nbuk; i += 256) bh[(size_t)b * nbuk + i] = h[i];
}

__global__ __launch_bounds__(256) void bucket_total(const int* __restrict__ bh,
                                                    int* __restrict__ T, int nbuk) {
    int buk = blockIdx.x * 256 + threadIdx.x;
    if (buk >= nbuk) return;
    int s = 0;
    for (int b = 0; b < NBLK; ++b) s += bh[(size_t)b * nbuk + buk];
    T[buk] = s;
}

__global__ __launch_bounds__(256) void bucket_scan(const int* __restrict__ T,
                                                   int* __restrict__ BB, int nbuk, int E) {
    __shared__ int sc[256];
    __shared__ int carry;
    if (threadIdx.x == 0) carry = 0;
    __syncthreads();
    for (int base = 0; base < nbuk; base += 256) {
        int i = base + threadIdx.x;
        int v = (i < nbuk) ? T[i] : 0;
        sc[threadIdx.x] = v;
        __syncthreads();
        for (int off = 1; off < 256; off <<= 1) {
            int t = (threadIdx.x >= off) ? sc[threadIdx.x - off] : 0;
            __syncthreads();
            sc[threadIdx.x] += t;
            __syncthreads();
        }
        if (i < nbuk) BB[i] = carry + sc[threadIdx.x] - v;
        __syncthreads();
        if (threadIdx.x == 255) carry += sc[255];
        __syncthreads();
    }
    if (threadIdx.x == 0) BB[nbuk] = E;
}

__global__ __launch_bounds__(256) void bucket_expand(const int* __restrict__ bh,
                                                     const int* __restrict__ BB,
                                                     int* __restrict__ off, int nbuk) {
    int buk = blockIdx.x * 256 + threadIdx.x;
    if (buk >= nbuk) return;
    int run = BB[buk];
    for (int b = 0; b < NBLK; ++b) {
        off[(size_t)b * nbuk + buk] = run;
        run += bh[(size_t)b * nbuk + buk];
    }
}

__global__ __launch_bounds__(256) void bucket_scatter(const int* __restrict__ src,
                                                      const int* __restrict__ dst,
                                                      const int* __restrict__ off,
                                                      int* __restrict__ eb,
                                                      int E, int nbuk, int chunk) {
    __shared__ int cur[MAXBUK];
    int b = blockIdx.x;
    for (int i = threadIdx.x; i < nbuk; i += 256) cur[i] = off[(size_t)b * nbuk + i];
    __syncthreads();
    int lo = b * chunk, hi = min(E, lo + chunk);
    for (int e = lo + threadIdx.x; e < hi; e += 256) {
        int d = dst[e], s = src[e];
        int pos = atomicAdd(&cur[d >> 6], 1);
        eb[pos] = (s << 6) | (d & 63);
    }
}

__global__ __launch_bounds__(256) void bucket_csr(const int* __restrict__ eb,
                                                  const int* __restrict__ BB,
                                                  int* __restrict__ startA,
                                                  float* __restrict__ dinv,
                                                  int* __restrict__ col,
                                                  int N, int E) {
    __shared__ int h[64];
    int b = blockIdx.x;
    int bs = BB[b], be = BB[b + 1];
    if (threadIdx.x < 64) h[threadIdx.x] = 0;
    __syncthreads();
    for (int i = bs + threadIdx.x; i < be; i += 256) atomicAdd(&h[eb[i] & 63], 1);
    __syncthreads();
    if (threadIdx.x < 64) {  // wave 0
        int v = h[threadIdx.x];
        int incl = v;
#pragma unroll
        for (int o = 1; o < 64; o <<= 1) {
            int t = __shfl_up(incl, o, 64);
            if ((int)threadIdx.x >= o) incl += t;
        }
        int n = (b << 6) + threadIdx.x;
        if (n < N) {
            startA[n] = bs + incl - v;
            dinv[n] = rsqrtf((float)(v + 1));  // +1 self-loop
        }
        h[threadIdx.x] = incl - v;  // reuse as cursor
    }
    __syncthreads();
    for (int i = bs + threadIdx.x; i < be; i += 256) {
        int pk = eb[i];
        int pos = bs + atomicAdd(&h[pk & 63], 1);
        col[pos] = pk >> 6;
    }
    if (b == 0 && threadIdx.x == 0) startA[N] = E;
}

// --------------------------- MFMA GEMM ----------------------------------
template <int K, int BM, int BN, int WM, int WN, bool GUARDN, bool AHALF>
__global__ __launch_bounds__(256) void gemm_mfma(const void* __restrict__ Ap,
                                                 const float* __restrict__ W,
                                                 const float* __restrict__ dinv,
                                                 f16* __restrict__ C, int M, int N) {
    constexpr int KC = 64;
    __shared__ f16 As[BM * KC];
    __shared__ f16 Bs[BN * KC];
    __shared__ float sdinv[BM];
    const int t = threadIdx.x;
    const int wid = t >> 6, lane = t & 63;
    const int wm = wid % WM, wn = wid / WM;
    const int row0 = blockIdx.x * BM;

    for (int i = t; i < BM; i += 256) {
        int r = row0 + i;
        sdinv[i] = dinv[r < M ? r : M - 1];
    }

    f32x4 acc[4][4] = {};

    for (int k0 = 0; k0 < K; k0 += KC) {
        if (AHALF) {
            const f16* A = (const f16*)Ap;
#pragma unroll
            for (int i = 0; i < BM / 32; ++i) {
                int g = t + i * 256;
                int r = g >> 3, c = g & 7;
                int grow = row0 + r; if (grow >= M) grow = M - 1;
                f16x8 v = *reinterpret_cast<const f16x8*>(&A[(size_t)grow * K + k0 + c * 8]);
                *reinterpret_cast<f16x8*>(&As[r * 64 + ((c ^ (r & 7)) << 3)]) = v;
            }
        } else {
            const float* A = (const float*)Ap;
#pragma unroll
            for (int i = 0; i < BM / 32; ++i) {
                int g = t + i * 256;
                int r = g >> 3, c = g & 7;
                int grow = row0 + r; if (grow >= M) grow = M - 1;
                const float* s = &A[(size_t)grow * K + k0 + c * 8];
                float4 a = *reinterpret_cast<const float4*>(s);
                float4 b = *reinterpret_cast<const float4*>(s + 4);
                f16x8 v = {(f16)a.x, (f16)a.y, (f16)a.z, (f16)a.w,
                           (f16)b.x, (f16)b.y, (f16)b.z, (f16)b.w};
                *reinterpret_cast<f16x8*>(&As[r * 64 + ((c ^ (r & 7)) << 3)]) = v;
            }
        }
        if (!GUARDN) {
#pragma unroll
            for (int i = 0; i < BN / 16; ++i) {
                int v = t + i * 256;
                int kk = v / (BN / 4), nq = v % (BN / 4);
                float4 w = *reinterpret_cast<const float4*>(&W[(size_t)(k0 + kk) * N + nq * 4]);
                float ws[4] = {w.x, w.y, w.z, w.w};
#pragma unroll
                for (int j = 0; j < 4; ++j) {
                    int n = nq * 4 + j;
                    Bs[n * 64 + (((kk >> 3) ^ (n & 7)) << 3) + (kk & 7)] = (f16)ws[j];
                }
            }
        } else {
#pragma unroll
            for (int i = 0; i < BN / 16; ++i) {
                int v = t + i * 256;
                int kk = v / (BN / 4), nq = v % (BN / 4);
#pragma unroll
                for (int j = 0; j < 4; ++j) {
                    int n = nq * 4 + j;
                    float wv = (n < N) ? W[(size_t)(k0 + kk) * N + n] : 0.f;
                    Bs[n * 64 + (((kk >> 3) ^ (n & 7)) << 3) + (kk & 7)] = (f16)wv;
                }
            }
        }
        __syncthreads();

#pragma unroll
        for (int s = 0; s < 2; ++s) {
            f16x8 af[4], bf[4];
            int c = s * 4 + (lane >> 4);
#pragma unroll
            for (int mf = 0; mf < 4; ++mf) {
                int r = wm * 64 + mf * 16 + (lane & 15);
                af[mf] = *reinterpret_cast<const f16x8*>(&As[r * 64 + ((c ^ (r & 7)) << 3)]);
            }
#pragma unroll
            for (int nf = 0; nf < 4; ++nf) {
                int n = wn * 64 + nf * 16 + (lane & 15);
                bf[nf] = *reinterpret_cast<const f16x8*>(&Bs[n * 64 + ((c ^ (n & 7)) << 3)]);
            }
#pragma unroll
            for (int mf = 0; mf < 4; ++mf)
#pragma unroll
                for (int nf = 0; nf < 4; ++nf)
                    acc[mf][nf] = __builtin_amdgcn_mfma_f32_16x16x32_f16(af[mf], bf[nf],
                                                                         acc[mf][nf], 0, 0, 0);
        }
        __syncthreads();
    }

#pragma unroll
    for (int mf = 0; mf < 4; ++mf) {
#pragma unroll
        for (int q = 0; q < 4; ++q) {
            int lr = wm * 64 + mf * 16 + (lane >> 4) * 4 + q;
            int grow = row0 + lr;
            if (grow < M) {
                float scl = sdinv[lr];
#pragma unroll
                for (int nf = 0; nf < 4; ++nf) {
                    int gcol = wn * 64 + nf * 16 + (lane & 15);
                    if (!GUARDN || gcol < N)
                        C[(size_t)grow * N + gcol] = (f16)(acc[mf][nf][q] * scl);
                }
            }
        }
    }
}

// --------------------------- Aggregation --------------------------------
// XCD-pinned feature slices: slice = blockIdx & 7 -> (round-robin dispatch)
// all blocks of slice s land on XCD s, whose L2 then only caches that
// 16-feature slice of m (N*16*2B = 3.2MB < 4MB L2). col is streamed with
// nontemporal loads so it doesn't evict the slice. 8 lanes per node-walker
// (half2/lane = 16 features), 32 walkers/block, 64-node blocks.
__global__ __launch_bounds__(256) void agg_h_slice(
        const __half* __restrict__ m, const int* __restrict__ col,
        const int* __restrict__ start,
        const float* __restrict__ dinv, const float* __restrict__ bias,
        __half* __restrict__ out, int N) {
    const int slice = blockIdx.x & 7;
    const int nb = blockIdx.x >> 3;
    const int walker = threadIdx.x >> 3;   // 0..31
    const int fl = threadIdx.x & 7;        // feature lane within slice
    const __half2* mp = reinterpret_cast<const __half2*>(m) + slice * 8 + fl;
    const float2 b2 = *reinterpret_cast<const float2*>(&bias[slice * 16 + fl * 2]);
#pragma unroll
    for (int r = 0; r < 2; ++r) {
        int n = (nb << 6) + (r << 5) + walker;
        if (n < N) {
            int s = start[n], e = start[n + 1];
            float ax = 0.f, ay = 0.f, bx = 0.f, by = 0.f;
            float cx = 0.f, cy = 0.f, dx = 0.f, dy = 0.f;
            int p = s;
            for (; p + 4 <= e; p += 4) {
                int j0 = __builtin_nontemporal_load(&col[p]);
                int j1 = __builtin_nontemporal_load(&col[p + 1]);
                int j2 = __builtin_nontemporal_load(&col[p + 2]);
                int j3 = __builtin_nontemporal_load(&col[p + 3]);
                __half2 v0 = mp[(size_t)j0 * 64];
                __half2 v1 = mp[(size_t)j1 * 64];
                __half2 v2 = mp[(size_t)j2 * 64];
                __half2 v3 = mp[(size_t)j3 * 64];
                float2 f0 = __half22float2(v0), f1 = __half22float2(v1);
                float2 f2 = __half22float2(v2), f3 = __half22float2(v3);
                ax += f0.x; ay += f0.y; bx += f1.x; by += f1.y;
                cx += f2.x; cy += f2.y; dx += f3.x; dy += f3.y;
            }
            for (; p < e; ++p) {
                int j = __builtin_nontemporal_load(&col[p]);
                float2 f = __half22float2(mp[(size_t)j * 64]);
                ax += f.x; ay += f.y;
            }
            float2 fi = __half22float2(mp[(size_t)n * 64]);
            ax += fi.x; ay += fi.y;
            float di = dinv[n];
            float ox = fmaxf(fmaf(di, (ax + bx) + (cx + dx), b2.x), 0.f);
            float oy = fmaxf(fmaf(di, (ay + by) + (cy + dy), b2.y), 0.f);
            __half2 ho = __floats2half2_rn(ox, oy);
            unsigned int u = *reinterpret_cast<unsigned int*>(&ho);
            __builtin_nontemporal_store(
                u, reinterpret_cast<unsigned int*>(out) + (size_t)n * 64 + slice * 8 + fl);
        }
    }
}

// Final layer: F=40 fp16 m + bias + ReLU + log_softmax (R3-style 8-deep).
__global__ __launch_bounds__(256) void agg_out_kernel(
        const __half* __restrict__ m, const int* __restrict__ col,
        const int* __restrict__ start,
        const float* __restrict__ dinv, const float* __restrict__ bias,
        float* __restrict__ out, int N) {
    int w = (int)((blockIdx.x * 256 + threadIdx.x) >> 6);
    int lane = threadIdx.x & 63;
    if (w >= N) return;
    bool act = lane < NCLASS;
    int cl = act ? lane : 0;
    int s = start[w];
    int e = start[w + 1];
    float a0 = 0.f, a1 = 0.f;
    int p = s;
    for (; p + 8 <= e; p += 8) {
        int j[8];
#pragma unroll
        for (int u = 0; u < 8; ++u) j[u] = __builtin_nontemporal_load(&col[p + u]);
        __half v[8];
#pragma unroll
        for (int u = 0; u < 8; ++u) v[u] = m[(size_t)j[u] * NCLASS + cl];
#pragma unroll
        for (int u = 0; u < 8; ++u) {
            if (u & 1) a1 += __half2float(v[u]);
            else       a0 += __half2float(v[u]);
        }
    }
    for (; p < e; ++p) a0 += __half2float(m[(size_t)col[p] * NCLASS + cl]);
    a0 += __half2float(m[(size_t)w * NCLASS + cl]);
    float di = dinv[w];
    float h = fmaxf(fmaf(di, a0 + a1, bias[cl]), 0.f);
    float hm = act ? h : -INFINITY;
#pragma unroll
    for (int off = 32; off; off >>= 1) hm = fmaxf(hm, __shfl_xor(hm, off, 64));
    float ex = act ? expf(h - hm) : 0.f;
    float se = ex;
#pragma unroll
    for (int off = 32; off; off >>= 1) se += __shfl_xor(se, off, 64);
    if (act) out[(size_t)w * NCLASS + lane] = h - hm - logf(se);
}

// ------------------------------ launch -----------------------------------

extern "C" void kernel_launch(void* const* d_in, const int* in_sizes, int n_in,
                              void* d_out, int out_size, void* d_ws, size_t ws_size,
                              hipStream_t stream) {
    const float* x  = (const float*)d_in[0];
    const int*   ei = (const int*)d_in[1];
    const float* W0 = (const float*)d_in[2];
    const float* b0 = (const float*)d_in[3];
    const float* W1 = (const float*)d_in[4];
    const float* b1 = (const float*)d_in[5];
    const float* W2 = (const float*)d_in[6];
    const float* b2 = (const float*)d_in[7];
    float* out = (float*)d_out;

    const int NFEATr = 256;
    const int N = in_sizes[0] / NFEATr;  // 100000
    const int E = in_sizes[1] / 2;       // 1600000
    const int* src = ei;
    const int* dst = ei + E;

    const int nbuk = (N + 63) >> 6;      // 1563
    const int chunk = (E + NBLK - 1) / NBLK;

    char* p = (char*)d_ws;
    auto alloc = [&](size_t bytes) -> void* {
        void* r = (void*)p;
        p += (bytes + 255) & ~(size_t)255;
        return r;
    };
    int*    bh     = (int*)alloc((size_t)NBLK * nbuk * 4);
    int*    T      = (int*)alloc((size_t)nbuk * 4);
    int*    BB     = (int*)alloc((size_t)(nbuk + 1) * 4);
    int*    offb   = (int*)alloc((size_t)NBLK * nbuk * 4);
    int*    eb     = (int*)alloc((size_t)E * 4);
    int*    col    = (int*)alloc((size_t)E * 4);
    int*    startA = (int*)alloc((size_t)(N + 1) * 4);
    float*  dinv   = (float*)alloc((size_t)N * 4);
    f16*    mbuf   = (f16*)alloc((size_t)N * NHID * 2);
    f16*    hbuf   = (f16*)alloc((size_t)N * NHID * 2);

    int nbl7 = (nbuk + 255) / 256;

    bucket_hist<<<NBLK, 256, 0, stream>>>(dst, bh, E, nbuk, chunk);
    bucket_total<<<nbl7, 256, 0, stream>>>(bh, T, nbuk);
    bucket_scan<<<1, 256, 0, stream>>>(T, BB, nbuk, E);
    bucket_expand<<<nbl7, 256, 0, stream>>>(bh, BB, offb, nbuk);
    bucket_scatter<<<NBLK, 256, 0, stream>>>(src, dst, offb, eb, E, nbuk, chunk);
    bucket_csr<<<nbuk, 256, 0, stream>>>(eb, BB, startA, dinv, col, N, E);

    int abl = (N + 3) / 4;
    int aggblk = nbuk * 8;   // 8 XCD-pinned feature slices
    int g128 = (N + 127) / 128;
    int g256 = (N + 255) / 256;

    // layer 0: x fp32 [N,256] @ W0 -> mbuf f16 (pre-scaled by dinv[row])
    gemm_mfma<256, 128, 128, 2, 2, false, false><<<g128, 256, 0, stream>>>(
        (const void*)x, W0, dinv, mbuf, N, NHID);
    agg_h_slice<<<aggblk, 256, 0, stream>>>((const __half*)mbuf, col, startA, dinv, b0,
                                            (__half*)hbuf, N);

    // layer 1
    gemm_mfma<128, 128, 128, 2, 2, false, true><<<g128, 256, 0, stream>>>(
        (const void*)hbuf, W1, dinv, mbuf, N, NHID);
    agg_h_slice<<<aggblk, 256, 0, stream>>>((const __half*)mbuf, col, startA, dinv, b1,
                                            (__half*)hbuf, N);

    // layer 2 (40-wide messages)
    gemm_mfma<128, 256, 64, 4, 1, true, true><<<g256, 256, 0, stream>>>(
        (const void*)hbuf, W2, dinv, mbuf, N, NCLASS);
    agg_out_kernel<<<abl, 256, 0, stream>>>((const __half*)mbuf, col, startA, dinv, b2,
                                            out, N);
}

// Round 7
// 407.784 us; speedup vs baseline: 1.7491x; 1.7491x over previous
//
#include <hip/hip_runtime.h>
#include <hip/hip_bf16.h>
#include <hip/hip_fp16.h>
#include <math.h>

#define NHID 128
#define NCLASS 40
#define NBLK 256          // edge-chunk blocks for bucket passes
#define MAXBUK 1600       // >= ceil(N/64)

typedef _Float16 f16;
typedef f16 f16x8 __attribute__((ext_vector_type(8)));
typedef float f32x4 __attribute__((ext_vector_type(4)));

// ---------------- CSR build: 2-level counting sort (LDS atomics only) ----
// eb entries packed: (src << 6) | (dst & 63)

__global__ __launch_bounds__(256) void bucket_total(const int* __restrict__ bh,
                                                    int* __restrict__ T, int nbuk) {
    int buk = blockIdx.x * 256 + threadIdx.x;
    if (buk >= nbuk) return;
    int s = 0;
    for (int b = 0; b < NBLK; ++b) s += bh[(size_t)b * nbuk + buk];
    T[buk] = s;
}

__global__ __launch_bounds__(256) void bucket_scan(const int* __restrict__ T,
                                                   int* __restrict__ BB, int nbuk, int E) {
    __shared__ int sc[256];
    __shared__ int carry;
    if (threadIdx.x == 0) carry = 0;
    __syncthreads();
    for (int base = 0; base < nbuk; base += 256) {
        int i = base + threadIdx.x;
        int v = (i < nbuk) ? T[i] : 0;
        sc[threadIdx.x] = v;
        __syncthreads();
        for (int off = 1; off < 256; off <<= 1) {
            int t = (threadIdx.x >= off) ? sc[threadIdx.x - off] : 0;
            __syncthreads();
            sc[threadIdx.x] += t;
            __syncthreads();
        }
        if (i < nbuk) BB[i] = carry + sc[threadIdx.x] - v;
        __syncthreads();
        if (threadIdx.x == 255) carry += sc[255];
        __syncthreads();
    }
    if (threadIdx.x == 0) BB[nbuk] = E;
}

__global__ __launch_bounds__(256) void bucket_expand(const int* __restrict__ bh,
                                                     const int* __restrict__ BB,
                                                     int* __restrict__ off, int nbuk) {
    int buk = blockIdx.x * 256 + threadIdx.x;
    if (buk >= nbuk) return;
    int run = BB[buk];
    for (int b = 0; b < NBLK; ++b) {
        off[(size_t)b * nbuk + buk] = run;
        run += bh[(size_t)b * nbuk + buk];
    }
}

__global__ __launch_bounds__(256) void bucket_scatter(const int* __restrict__ src,
                                                      const int* __restrict__ dst,
                                                      const int* __restrict__ off,
                                                      int* __restrict__ eb,
                                                      int E, int nbuk, int chunk) {
    __shared__ int cur[MAXBUK];
    int b = blockIdx.x;
    for (int i = threadIdx.x; i < nbuk; i += 256) cur[i] = off[(size_t)b * nbuk + i];
    __syncthreads();
    int lo = b * chunk, hi = min(E, lo + chunk);
    for (int e = lo + threadIdx.x; e < hi; e += 256) {
        int d = dst[e], s = src[e];
        int pos = atomicAdd(&cur[d >> 6], 1);
        eb[pos] = (s << 6) | (d & 63);
    }
}

__global__ __launch_bounds__(256) void bucket_csr(const int* __restrict__ eb,
                                                  const int* __restrict__ BB,
                                                  int* __restrict__ startA,
                                                  float* __restrict__ dinv,
                                                  int* __restrict__ col,
                                                  int N, int E) {
    __shared__ int h[64];
    int b = blockIdx.x;
    int bs = BB[b], be = BB[b + 1];
    if (threadIdx.x < 64) h[threadIdx.x] = 0;
    __syncthreads();
    for (int i = bs + threadIdx.x; i < be; i += 256) atomicAdd(&h[eb[i] & 63], 1);
    __syncthreads();
    if (threadIdx.x < 64) {  // wave 0
        int v = h[threadIdx.x];
        int incl = v;
#pragma unroll
        for (int o = 1; o < 64; o <<= 1) {
            int t = __shfl_up(incl, o, 64);
            if ((int)threadIdx.x >= o) incl += t;
        }
        int n = (b << 6) + threadIdx.x;
        if (n < N) {
            startA[n] = bs + incl - v;
            dinv[n] = rsqrtf((float)(v + 1));  // +1 self-loop
        }
        h[threadIdx.x] = incl - v;  // reuse as cursor
    }
    __syncthreads();
    for (int i = bs + threadIdx.x; i < be; i += 256) {
        int pk = eb[i];
        int pos = bs + atomicAdd(&h[pk & 63], 1);
        col[pos] = pk >> 6;
    }
    if (b == 0 && threadIdx.x == 0) startA[N] = E;
}

// -------------- FUSED: gemm0 (x@W0 -> fp16, unscaled) || bucket_hist ------
// Blocks [0,GB): MFMA gemm tiles. Blocks [GB, GB+NBLK): per-chunk coarse
// histogram (bucket = dst>>6) with LDS atomics. Independent work overlapped
// in a single dispatch. LDS: union of gemm tiles (32KB) and hist (6.4KB).
__global__ __launch_bounds__(256) void gemm0_hist(
        const float* __restrict__ A, const float* __restrict__ W,
        f16* __restrict__ C, int M,
        const int* __restrict__ dst, int* __restrict__ bh,
        int E, int nbuk, int chunk, int GB) {
    __shared__ union {
        struct { f16 As[128 * 64]; f16 Bs[128 * 64]; } g;
        int h[MAXBUK];
    } sh;

    if ((int)blockIdx.x >= GB) {
        // ---------------- hist path ----------------
        int b = blockIdx.x - GB;
        for (int i = threadIdx.x; i < nbuk; i += 256) sh.h[i] = 0;
        __syncthreads();
        int lo = b * chunk, hi = min(E, lo + chunk);
        for (int e = lo + threadIdx.x; e < hi; e += 256)
            atomicAdd(&sh.h[dst[e] >> 6], 1);
        __syncthreads();
        for (int i = threadIdx.x; i < nbuk; i += 256) bh[(size_t)b * nbuk + i] = sh.h[i];
        return;
    }
    // ---------------- gemm path: C = A[M x 256] @ W[256 x 128] ------------
    const int t = threadIdx.x;
    const int wid = t >> 6, lane = t & 63;
    const int wm = wid & 1, wn = wid >> 1;
    const int row0 = blockIdx.x * 128;

    f32x4 acc[4][4] = {};

    for (int k0 = 0; k0 < 256; k0 += 64) {
#pragma unroll
        for (int i = 0; i < 4; ++i) {
            int g = t + i * 256;
            int r = g >> 3, c = g & 7;
            int grow = row0 + r; if (grow >= M) grow = M - 1;
            const float* s = &A[(size_t)grow * 256 + k0 + c * 8];
            float4 a = *reinterpret_cast<const float4*>(s);
            float4 b = *reinterpret_cast<const float4*>(s + 4);
            f16x8 v = {(f16)a.x, (f16)a.y, (f16)a.z, (f16)a.w,
                       (f16)b.x, (f16)b.y, (f16)b.z, (f16)b.w};
            *reinterpret_cast<f16x8*>(&sh.g.As[r * 64 + ((c ^ (r & 7)) << 3)]) = v;
        }
#pragma unroll
        for (int i = 0; i < 8; ++i) {
            int v = t + i * 256;
            int kk = v >> 5, nq = v & 31;
            float4 w = *reinterpret_cast<const float4*>(&W[(size_t)(k0 + kk) * NHID + nq * 4]);
            float ws[4] = {w.x, w.y, w.z, w.w};
#pragma unroll
            for (int j = 0; j < 4; ++j) {
                int n = nq * 4 + j;
                sh.g.Bs[n * 64 + (((kk >> 3) ^ (n & 7)) << 3) + (kk & 7)] = (f16)ws[j];
            }
        }
        __syncthreads();

#pragma unroll
        for (int s = 0; s < 2; ++s) {
            f16x8 af[4], bf[4];
            int c = s * 4 + (lane >> 4);
#pragma unroll
            for (int mf = 0; mf < 4; ++mf) {
                int r = wm * 64 + mf * 16 + (lane & 15);
                af[mf] = *reinterpret_cast<const f16x8*>(&sh.g.As[r * 64 + ((c ^ (r & 7)) << 3)]);
            }
#pragma unroll
            for (int nf = 0; nf < 4; ++nf) {
                int n = wn * 64 + nf * 16 + (lane & 15);
                bf[nf] = *reinterpret_cast<const f16x8*>(&sh.g.Bs[n * 64 + ((c ^ (n & 7)) << 3)]);
            }
#pragma unroll
            for (int mf = 0; mf < 4; ++mf)
#pragma unroll
                for (int nf = 0; nf < 4; ++nf)
                    acc[mf][nf] = __builtin_amdgcn_mfma_f32_16x16x32_f16(af[mf], bf[nf],
                                                                         acc[mf][nf], 0, 0, 0);
        }
        __syncthreads();
    }

#pragma unroll
    for (int mf = 0; mf < 4; ++mf) {
#pragma unroll
        for (int q = 0; q < 4; ++q) {
            int lr = wm * 64 + mf * 16 + (lane >> 4) * 4 + q;
            int grow = row0 + lr;
            if (grow < M) {
#pragma unroll
                for (int nf = 0; nf < 4; ++nf) {
                    int gcol = wn * 64 + nf * 16 + (lane & 15);
                    C[(size_t)grow * NHID + gcol] = (f16)acc[mf][nf][q];
                }
            }
        }
    }
}

// --------------------------- MFMA GEMM (unscaled out) --------------------
template <int K, int BM, int BN, int WM, int WN, bool GUARDN>
__global__ __launch_bounds__(256) void gemm_mfma(const f16* __restrict__ A,
                                                 const float* __restrict__ W,
                                                 f16* __restrict__ C, int M, int N) {
    constexpr int KC = 64;
    __shared__ f16 As[BM * KC];
    __shared__ f16 Bs[BN * KC];
    const int t = threadIdx.x;
    const int wid = t >> 6, lane = t & 63;
    const int wm = wid % WM, wn = wid / WM;
    const int row0 = blockIdx.x * BM;

    f32x4 acc[4][4] = {};

    for (int k0 = 0; k0 < K; k0 += KC) {
#pragma unroll
        for (int i = 0; i < BM / 32; ++i) {
            int g = t + i * 256;
            int r = g >> 3, c = g & 7;
            int grow = row0 + r; if (grow >= M) grow = M - 1;
            f16x8 v = *reinterpret_cast<const f16x8*>(&A[(size_t)grow * K + k0 + c * 8]);
            *reinterpret_cast<f16x8*>(&As[r * 64 + ((c ^ (r & 7)) << 3)]) = v;
        }
        if (!GUARDN) {
#pragma unroll
            for (int i = 0; i < BN / 16; ++i) {
                int v = t + i * 256;
                int kk = v / (BN / 4), nq = v % (BN / 4);
                float4 w = *reinterpret_cast<const float4*>(&W[(size_t)(k0 + kk) * N + nq * 4]);
                float ws[4] = {w.x, w.y, w.z, w.w};
#pragma unroll
                for (int j = 0; j < 4; ++j) {
                    int n = nq * 4 + j;
                    Bs[n * 64 + (((kk >> 3) ^ (n & 7)) << 3) + (kk & 7)] = (f16)ws[j];
                }
            }
        } else {
#pragma unroll
            for (int i = 0; i < BN / 16; ++i) {
                int v = t + i * 256;
                int kk = v / (BN / 4), nq = v % (BN / 4);
#pragma unroll
                for (int j = 0; j < 4; ++j) {
                    int n = nq * 4 + j;
                    float wv = (n < N) ? W[(size_t)(k0 + kk) * N + n] : 0.f;
                    Bs[n * 64 + (((kk >> 3) ^ (n & 7)) << 3) + (kk & 7)] = (f16)wv;
                }
            }
        }
        __syncthreads();

#pragma unroll
        for (int s = 0; s < 2; ++s) {
            f16x8 af[4], bf[4];
            int c = s * 4 + (lane >> 4);
#pragma unroll
            for (int mf = 0; mf < 4; ++mf) {
                int r = wm * 64 + mf * 16 + (lane & 15);
                af[mf] = *reinterpret_cast<const f16x8*>(&As[r * 64 + ((c ^ (r & 7)) << 3)]);
            }
#pragma unroll
            for (int nf = 0; nf < 4; ++nf) {
                int n = wn * 64 + nf * 16 + (lane & 15);
                bf[nf] = *reinterpret_cast<const f16x8*>(&Bs[n * 64 + ((c ^ (n & 7)) << 3)]);
            }
#pragma unroll
            for (int mf = 0; mf < 4; ++mf)
#pragma unroll
                for (int nf = 0; nf < 4; ++nf)
                    acc[mf][nf] = __builtin_amdgcn_mfma_f32_16x16x32_f16(af[mf], bf[nf],
                                                                         acc[mf][nf], 0, 0, 0);
        }
        __syncthreads();
    }

#pragma unroll
    for (int mf = 0; mf < 4; ++mf) {
#pragma unroll
        for (int q = 0; q < 4; ++q) {
            int lr = wm * 64 + mf * 16 + (lane >> 4) * 4 + q;
            int grow = row0 + lr;
            if (grow < M) {
#pragma unroll
                for (int nf = 0; nf < 4; ++nf) {
                    int gcol = wn * 64 + nf * 16 + (lane & 15);
                    if (!GUARDN || gcol < N)
                        C[(size_t)grow * N + gcol] = (f16)acc[mf][nf][q];
                }
            }
        }
    }
}

// --------------------------- Aggregation --------------------------------
// One wave per node, full-row 256B gathers (m unscaled fp16). Per-edge
// weight dinv[j] is a wave-uniform broadcast load (dinv 400KB, L2-resident).
__global__ __launch_bounds__(256) void agg_h_kernel(
        const __half* __restrict__ m, const int* __restrict__ col,
        const int* __restrict__ start,
        const float* __restrict__ dinv, const float* __restrict__ bias,
        __half* __restrict__ out, int N) {
    int w = (int)((blockIdx.x * 256 + threadIdx.x) >> 6);
    int lane = threadIdx.x & 63;
    if (w >= N) return;
    const __half2* mp = reinterpret_cast<const __half2*>(m);
    int s = start[w];
    int e = start[w + 1];
    float ax = 0.f, ay = 0.f, bx = 0.f, by = 0.f;
    int p = s;
    for (; p < e && (p & 3); ++p) {
        int j = col[p];
        float wt = dinv[j];
        float2 f = __half22float2(mp[(size_t)j * 64 + lane]);
        ax = fmaf(wt, f.x, ax); ay = fmaf(wt, f.y, ay);
    }
    for (; p + 8 <= e; p += 8) {
        int4 c0 = *reinterpret_cast<const int4*>(&col[p]);
        int4 c1 = *reinterpret_cast<const int4*>(&col[p + 4]);
        int j[8] = {c0.x, c0.y, c0.z, c0.w, c1.x, c1.y, c1.z, c1.w};
        __half2 v[8];
        float wt[8];
#pragma unroll
        for (int u = 0; u < 8; ++u) {
            v[u] = mp[(size_t)j[u] * 64 + lane];
            wt[u] = dinv[j[u]];
        }
#pragma unroll
        for (int u = 0; u < 8; ++u) {
            float2 f = __half22float2(v[u]);
            if (u & 1) { bx = fmaf(wt[u], f.x, bx); by = fmaf(wt[u], f.y, by); }
            else       { ax = fmaf(wt[u], f.x, ax); ay = fmaf(wt[u], f.y, ay); }
        }
    }
    for (; p + 4 <= e; p += 4) {
        int4 c = *reinterpret_cast<const int4*>(&col[p]);
        int j[4] = {c.x, c.y, c.z, c.w};
        __half2 v[4];
        float wt[4];
#pragma unroll
        for (int u = 0; u < 4; ++u) {
            v[u] = mp[(size_t)j[u] * 64 + lane];
            wt[u] = dinv[j[u]];
        }
#pragma unroll
        for (int u = 0; u < 4; ++u) {
            float2 f = __half22float2(v[u]);
            if (u & 1) { bx = fmaf(wt[u], f.x, bx); by = fmaf(wt[u], f.y, by); }
            else       { ax = fmaf(wt[u], f.x, ax); ay = fmaf(wt[u], f.y, ay); }
        }
    }
    for (; p < e; ++p) {
        int j = col[p];
        float wt = dinv[j];
        float2 f = __half22float2(mp[(size_t)j * 64 + lane]);
        ax = fmaf(wt, f.x, ax); ay = fmaf(wt, f.y, ay);
    }
    float di = dinv[w];
    float2 fi = __half22float2(mp[(size_t)w * 64 + lane]);
    ax = fmaf(di, fi.x, ax); ay = fmaf(di, fi.y, ay);
    float ox = fmaxf(fmaf(di, ax + bx, bias[lane * 2]), 0.f);
    float oy = fmaxf(fmaf(di, ay + by, bias[lane * 2 + 1]), 0.f);
    reinterpret_cast<__half2*>(out)[(size_t)w * 64 + lane] = __floats2half2_rn(ox, oy);
}

// Final layer: F=40 fp16 m + dinv weights + bias + ReLU + log_softmax.
__global__ __launch_bounds__(256) void agg_out_kernel(
        const __half* __restrict__ m, const int* __restrict__ col,
        const int* __restrict__ start,
        const float* __restrict__ dinv, const float* __restrict__ bias,
        float* __restrict__ out, int N) {
    int w = (int)((blockIdx.x * 256 + threadIdx.x) >> 6);
    int lane = threadIdx.x & 63;
    if (w >= N) return;
    bool act = lane < NCLASS;
    int cl = act ? lane : 0;
    int s = start[w];
    int e = start[w + 1];
    float a0 = 0.f, a1 = 0.f;
    int p = s;
    for (; p + 8 <= e; p += 8) {
        int j[8];
#pragma unroll
        for (int u = 0; u < 8; ++u) j[u] = col[p + u];
        __half v[8];
        float wt[8];
#pragma unroll
        for (int u = 0; u < 8; ++u) {
            v[u] = m[(size_t)j[u] * NCLASS + cl];
            wt[u] = dinv[j[u]];
        }
#pragma unroll
        for (int u = 0; u < 8; ++u) {
            if (u & 1) a1 = fmaf(wt[u], __half2float(v[u]), a1);
            else       a0 = fmaf(wt[u], __half2float(v[u]), a0);
        }
    }
    for (; p < e; ++p) {
        int j = col[p];
        a0 = fmaf(dinv[j], __half2float(m[(size_t)j * NCLASS + cl]), a0);
    }
    float di = dinv[w];
    a0 = fmaf(di, __half2float(m[(size_t)w * NCLASS + cl]), a0);
    float h = fmaxf(fmaf(di, a0 + a1, bias[cl]), 0.f);
    float hm = act ? h : -INFINITY;
#pragma unroll
    for (int off = 32; off; off >>= 1) hm = fmaxf(hm, __shfl_xor(hm, off, 64));
    float ex = act ? expf(h - hm) : 0.f;
    float se = ex;
#pragma unroll
    for (int off = 32; off; off >>= 1) se += __shfl_xor(se, off, 64);
    if (act) out[(size_t)w * NCLASS + lane] = h - hm - logf(se);
}

// ------------------------------ launch -----------------------------------

extern "C" void kernel_launch(void* const* d_in, const int* in_sizes, int n_in,
                              void* d_out, int out_size, void* d_ws, size_t ws_size,
                              hipStream_t stream) {
    const float* x  = (const float*)d_in[0];
    const int*   ei = (const int*)d_in[1];
    const float* W0 = (const float*)d_in[2];
    const float* b0 = (const float*)d_in[3];
    const float* W1 = (const float*)d_in[4];
    const float* b1 = (const float*)d_in[5];
    const float* W2 = (const float*)d_in[6];
    const float* b2 = (const float*)d_in[7];
    float* out = (float*)d_out;

    const int NFEATr = 256;
    const int N = in_sizes[0] / NFEATr;  // 100000
    const int E = in_sizes[1] / 2;       // 1600000
    const int* src = ei;
    const int* dst = ei + E;

    const int nbuk = (N + 63) >> 6;      // 1563
    const int chunk = (E + NBLK - 1) / NBLK;

    char* p = (char*)d_ws;
    auto alloc = [&](size_t bytes) -> void* {
        void* r = (void*)p;
        p += (bytes + 255) & ~(size_t)255;
        return r;
    };
    int*    bh     = (int*)alloc((size_t)NBLK * nbuk * 4);
    int*    T      = (int*)alloc((size_t)nbuk * 4);
    int*    BB     = (int*)alloc((size_t)(nbuk + 1) * 4);
    int*    offb   = (int*)alloc((size_t)NBLK * nbuk * 4);
    int*    eb     = (int*)alloc((size_t)E * 4);
    int*    col    = (int*)alloc((size_t)E * 4);
    int*    startA = (int*)alloc((size_t)(N + 1) * 4);
    float*  dinv   = (float*)alloc((size_t)N * 4);
    f16*    mbuf   = (f16*)alloc((size_t)N * NHID * 2);
    f16*    hbuf   = (f16*)alloc((size_t)N * NHID * 2);

    int nbl7 = (nbuk + 255) / 256;
    int GB0 = (N + 127) / 128;           // gemm0 tile blocks

    // fused: gemm0 (x@W0, no dinv needed) overlapped with coarse histogram
    gemm0_hist<<<GB0 + NBLK, 256, 0, stream>>>(x, W0, mbuf, N,
                                               dst, bh, E, nbuk, chunk, GB0);
    bucket_total<<<nbl7, 256, 0, stream>>>(bh, T, nbuk);
    bucket_scan<<<1, 256, 0, stream>>>(T, BB, nbuk, E);
    bucket_expand<<<nbl7, 256, 0, stream>>>(bh, BB, offb, nbuk);
    bucket_scatter<<<NBLK, 256, 0, stream>>>(src, dst, offb, eb, E, nbuk, chunk);
    bucket_csr<<<nbuk, 256, 0, stream>>>(eb, BB, startA, dinv, col, N, E);

    int abl = (N + 3) / 4;
    int g128 = (N + 127) / 128;
    int g256 = (N + 255) / 256;

    // layer 0 aggregation
    agg_h_kernel<<<abl, 256, 0, stream>>>((const __half*)mbuf, col, startA, dinv, b0,
                                          (__half*)hbuf, N);
    // layer 1
    gemm_mfma<128, 128, 128, 2, 2, false><<<g128, 256, 0, stream>>>(hbuf, W1, mbuf, N, NHID);
    agg_h_kernel<<<abl, 256, 0, stream>>>((const __half*)mbuf, col, startA, dinv, b1,
                                          (__half*)hbuf, N);
    // layer 2 (40-wide messages)
    gemm_mfma<128, 256, 64, 4, 1, true><<<g256, 256, 0, stream>>>(hbuf, W2, mbuf, N, NCLASS);
    agg_out_kernel<<<abl, 256, 0, stream>>>((const __half*)mbuf, col, startA, dinv, b2,
                                            out, N);
}

// Round 8
// 380.532 us; speedup vs baseline: 1.8743x; 1.0716x over previous
//
#include <hip/hip_runtime.h>
#include <hip/hip_bf16.h>
#include <hip/hip_fp16.h>
#include <math.h>

#define NHID 128
#define NCLASS 40
#define NBLK 256          // edge-chunk blocks for bucket passes
#define MAXBUK 1600       // >= ceil(N/64)

typedef _Float16 f16;
typedef f16 f16x8 __attribute__((ext_vector_type(8)));
typedef float f32x4 __attribute__((ext_vector_type(4)));

// ---------------- CSR build: 2-level counting sort (LDS atomics only) ----
// eb entries packed: (src << 6) | (dst & 63)

__global__ __launch_bounds__(256) void bucket_hist(const int* __restrict__ dst,
                                                   int* __restrict__ bh,
                                                   int E, int nbuk, int chunk) {
    __shared__ int h[MAXBUK];
    for (int i = threadIdx.x; i < nbuk; i += 256) h[i] = 0;
    __syncthreads();
    int b = blockIdx.x;
    int lo = b * chunk, hi = min(E, lo + chunk);
    for (int e = lo + threadIdx.x; e < hi; e += 256) atomicAdd(&h[dst[e] >> 6], 1);
    __syncthreads();
    for (int i = threadIdx.x; i < nbuk; i += 256) bh[(size_t)b * nbuk + i] = h[i];
}

__global__ __launch_bounds__(256) void bucket_total(const int* __restrict__ bh,
                                                    int* __restrict__ T, int nbuk) {
    int buk = blockIdx.x * 256 + threadIdx.x;
    if (buk >= nbuk) return;
    int s = 0;
    for (int b = 0; b < NBLK; ++b) s += bh[(size_t)b * nbuk + buk];
    T[buk] = s;
}

__global__ __launch_bounds__(256) void bucket_scan(const int* __restrict__ T,
                                                   int* __restrict__ BB, int nbuk, int E) {
    __shared__ int sc[256];
    __shared__ int carry;
    if (threadIdx.x == 0) carry = 0;
    __syncthreads();
    for (int base = 0; base < nbuk; base += 256) {
        int i = base + threadIdx.x;
        int v = (i < nbuk) ? T[i] : 0;
        sc[threadIdx.x] = v;
        __syncthreads();
        for (int off = 1; off < 256; off <<= 1) {
            int t = (threadIdx.x >= off) ? sc[threadIdx.x - off] : 0;
            __syncthreads();
            sc[threadIdx.x] += t;
            __syncthreads();
        }
        if (i < nbuk) BB[i] = carry + sc[threadIdx.x] - v;
        __syncthreads();
        if (threadIdx.x == 255) carry += sc[255];
        __syncthreads();
    }
    if (threadIdx.x == 0) BB[nbuk] = E;
}

__global__ __launch_bounds__(256) void bucket_expand(const int* __restrict__ bh,
                                                     const int* __restrict__ BB,
                                                     int* __restrict__ off, int nbuk) {
    int buk = blockIdx.x * 256 + threadIdx.x;
    if (buk >= nbuk) return;
    int run = BB[buk];
    for (int b = 0; b < NBLK; ++b) {
        off[(size_t)b * nbuk + buk] = run;
        run += bh[(size_t)b * nbuk + buk];
    }
}

__global__ __launch_bounds__(256) void bucket_scatter(const int* __restrict__ src,
                                                      const int* __restrict__ dst,
                                                      const int* __restrict__ off,
                                                      int* __restrict__ eb,
                                                      int E, int nbuk, int chunk) {
    __shared__ int cur[MAXBUK];
    int b = blockIdx.x;
    for (int i = threadIdx.x; i < nbuk; i += 256) cur[i] = off[(size_t)b * nbuk + i];
    __syncthreads();
    int lo = b * chunk, hi = min(E, lo + chunk);
    for (int e = lo + threadIdx.x; e < hi; e += 256) {
        int d = dst[e], s = src[e];
        int pos = atomicAdd(&cur[d >> 6], 1);
        eb[pos] = (s << 6) | (d & 63);
    }
}

__global__ __launch_bounds__(256) void bucket_csr(const int* __restrict__ eb,
                                                  const int* __restrict__ BB,
                                                  int* __restrict__ startA,
                                                  float* __restrict__ dinv,
                                                  int* __restrict__ col,
                                                  int N, int E) {
    __shared__ int h[64];
    int b = blockIdx.x;
    int bs = BB[b], be = BB[b + 1];
    if (threadIdx.x < 64) h[threadIdx.x] = 0;
    __syncthreads();
    for (int i = bs + threadIdx.x; i < be; i += 256) atomicAdd(&h[eb[i] & 63], 1);
    __syncthreads();
    if (threadIdx.x < 64) {  // wave 0
        int v = h[threadIdx.x];
        int incl = v;
#pragma unroll
        for (int o = 1; o < 64; o <<= 1) {
            int t = __shfl_up(incl, o, 64);
            if ((int)threadIdx.x >= o) incl += t;
        }
        int n = (b << 6) + threadIdx.x;
        if (n < N) {
            startA[n] = bs + incl - v;
            dinv[n] = rsqrtf((float)(v + 1));  // +1 self-loop
        }
        h[threadIdx.x] = incl - v;  // reuse as cursor
    }
    __syncthreads();
    for (int i = bs + threadIdx.x; i < be; i += 256) {
        int pk = eb[i];
        int pos = bs + atomicAdd(&h[pk & 63], 1);
        col[pos] = pk >> 6;
    }
    if (b == 0 && threadIdx.x == 0) startA[N] = E;
}

// ----------------- W transpose/convert: Wt[n][k] f16 ---------------------
__global__ __launch_bounds__(256) void prep_w(const float* __restrict__ W1,
                                              const float* __restrict__ W2,
                                              f16* __restrict__ Wt1,
                                              f16* __restrict__ Wt2) {
    int idx = blockIdx.x * 256 + threadIdx.x;
    if (idx < 128 * 128) {
        int n = idx >> 7, k = idx & 127;
        Wt1[n * 128 + k] = (f16)W1[k * 128 + n];
    }
    idx -= 128 * 128;
    if (idx >= 0 && idx < 48 * 128) {
        int n = idx >> 7, k = idx & 127;
        Wt2[n * 128 + k] = (n < NCLASS) ? (f16)W2[k * NCLASS + n] : (f16)0.f;
    }
}

// --------------------------- MFMA GEMM (layer 0) -------------------------
// C = dinv[row] * (A @ W), fp16 out. R3-proven code.
template <int K, int BM, int BN, int WM, int WN, bool GUARDN, bool AHALF>
__global__ __launch_bounds__(256) void gemm_mfma(const void* __restrict__ Ap,
                                                 const float* __restrict__ W,
                                                 const float* __restrict__ dinv,
                                                 f16* __restrict__ C, int M, int N) {
    constexpr int KC = 64;
    __shared__ f16 As[BM * KC];
    __shared__ f16 Bs[BN * KC];
    __shared__ float sdinv[BM];
    const int t = threadIdx.x;
    const int wid = t >> 6, lane = t & 63;
    const int wm = wid % WM, wn = wid / WM;
    const int row0 = blockIdx.x * BM;

    for (int i = t; i < BM; i += 256) {
        int r = row0 + i;
        sdinv[i] = dinv[r < M ? r : M - 1];
    }

    f32x4 acc[4][4] = {};

    for (int k0 = 0; k0 < K; k0 += KC) {
        if (AHALF) {
            const f16* A = (const f16*)Ap;
#pragma unroll
            for (int i = 0; i < BM / 32; ++i) {
                int g = t + i * 256;
                int r = g >> 3, c = g & 7;
                int grow = row0 + r; if (grow >= M) grow = M - 1;
                f16x8 v = *reinterpret_cast<const f16x8*>(&A[(size_t)grow * K + k0 + c * 8]);
                *reinterpret_cast<f16x8*>(&As[r * 64 + ((c ^ (r & 7)) << 3)]) = v;
            }
        } else {
            const float* A = (const float*)Ap;
#pragma unroll
            for (int i = 0; i < BM / 32; ++i) {
                int g = t + i * 256;
                int r = g >> 3, c = g & 7;
                int grow = row0 + r; if (grow >= M) grow = M - 1;
                const float* s = &A[(size_t)grow * K + k0 + c * 8];
                float4 a = *reinterpret_cast<const float4*>(s);
                float4 b = *reinterpret_cast<const float4*>(s + 4);
                f16x8 v = {(f16)a.x, (f16)a.y, (f16)a.z, (f16)a.w,
                           (f16)b.x, (f16)b.y, (f16)b.z, (f16)b.w};
                *reinterpret_cast<f16x8*>(&As[r * 64 + ((c ^ (r & 7)) << 3)]) = v;
            }
        }
        if (!GUARDN) {
#pragma unroll
            for (int i = 0; i < BN / 16; ++i) {
                int v = t + i * 256;
                int kk = v / (BN / 4), nq = v % (BN / 4);
                float4 w = *reinterpret_cast<const float4*>(&W[(size_t)(k0 + kk) * N + nq * 4]);
                float ws[4] = {w.x, w.y, w.z, w.w};
#pragma unroll
                for (int j = 0; j < 4; ++j) {
                    int n = nq * 4 + j;
                    Bs[n * 64 + (((kk >> 3) ^ (n & 7)) << 3) + (kk & 7)] = (f16)ws[j];
                }
            }
        } else {
#pragma unroll
            for (int i = 0; i < BN / 16; ++i) {
                int v = t + i * 256;
                int kk = v / (BN / 4), nq = v % (BN / 4);
#pragma unroll
                for (int j = 0; j < 4; ++j) {
                    int n = nq * 4 + j;
                    float wv = (n < N) ? W[(size_t)(k0 + kk) * N + n] : 0.f;
                    Bs[n * 64 + (((kk >> 3) ^ (n & 7)) << 3) + (kk & 7)] = (f16)wv;
                }
            }
        }
        __syncthreads();

#pragma unroll
        for (int s = 0; s < 2; ++s) {
            f16x8 af[4], bf[4];
            int c = s * 4 + (lane >> 4);
#pragma unroll
            for (int mf = 0; mf < 4; ++mf) {
                int r = wm * 64 + mf * 16 + (lane & 15);
                af[mf] = *reinterpret_cast<const f16x8*>(&As[r * 64 + ((c ^ (r & 7)) << 3)]);
            }
#pragma unroll
            for (int nf = 0; nf < 4; ++nf) {
                int n = wn * 64 + nf * 16 + (lane & 15);
                bf[nf] = *reinterpret_cast<const f16x8*>(&Bs[n * 64 + ((c ^ (n & 7)) << 3)]);
            }
#pragma unroll
            for (int mf = 0; mf < 4; ++mf)
#pragma unroll
                for (int nf = 0; nf < 4; ++nf)
                    acc[mf][nf] = __builtin_amdgcn_mfma_f32_16x16x32_f16(af[mf], bf[nf],
                                                                         acc[mf][nf], 0, 0, 0);
        }
        __syncthreads();
    }

#pragma unroll
    for (int mf = 0; mf < 4; ++mf) {
#pragma unroll
        for (int q = 0; q < 4; ++q) {
            int lr = wm * 64 + mf * 16 + (lane >> 4) * 4 + q;
            int grow = row0 + lr;
            if (grow < M) {
                float scl = sdinv[lr];
#pragma unroll
                for (int nf = 0; nf < 4; ++nf) {
                    int gcol = wn * 64 + nf * 16 + (lane & 15);
                    if (!GUARDN || gcol < N)
                        C[(size_t)grow * N + gcol] = (f16)(acc[mf][nf][q] * scl);
                }
            }
        }
    }
}

// ---------------- FUSED aggregation + next-layer GEMM --------------------
// One wave per 16-node tile. Phase 1: gather prescaled m rows (R3 scheme),
// bias+ReLU, write h rows to 16x128 LDS tile (XOR chunk swizzle).
// Phase 2: 16x128 @ 128xNP via MFMA; B-frags from pre-transposed f16 Wt in
// global (L2-resident 32KB). Output prescaled by dinv[row] for next agg.
template <int NP, int NR>   // NP = padded out width (mult of 16), NR = real
__global__ __launch_bounds__(64) void agg_gemm(
        const __half* __restrict__ m, const int* __restrict__ col,
        const int* __restrict__ start, const float* __restrict__ dinv,
        const float* __restrict__ bias, const f16* __restrict__ Wt,
        f16* __restrict__ C, int N) {
    __shared__ f16 Hs[16 * 128];
    const int lane = threadIdx.x;
    const int row0 = blockIdx.x * 16;
    const __half2* mp = reinterpret_cast<const __half2*>(m);
    const float2 b2 = *reinterpret_cast<const float2*>(&bias[lane * 2]);

    // ---- phase 1: aggregate 16 nodes ----
    for (int i = 0; i < 16; ++i) {
        int n = row0 + i;
        if (n >= N) break;
        int s = start[n], e = start[n + 1];
        float ax = 0.f, ay = 0.f, bx = 0.f, by = 0.f;
        int p = s;
        for (; p < e && (p & 3); ++p) {
            float2 f = __half22float2(mp[(size_t)col[p] * 64 + lane]);
            ax += f.x; ay += f.y;
        }
        for (; p + 8 <= e; p += 8) {
            int4 c0 = *reinterpret_cast<const int4*>(&col[p]);
            int4 c1 = *reinterpret_cast<const int4*>(&col[p + 4]);
            int j[8] = {c0.x, c0.y, c0.z, c0.w, c1.x, c1.y, c1.z, c1.w};
            __half2 v[8];
#pragma unroll
            for (int u = 0; u < 8; ++u) v[u] = mp[(size_t)j[u] * 64 + lane];
#pragma unroll
            for (int u = 0; u < 8; ++u) {
                float2 f = __half22float2(v[u]);
                if (u & 1) { bx += f.x; by += f.y; }
                else       { ax += f.x; ay += f.y; }
            }
        }
        for (; p + 4 <= e; p += 4) {
            int4 c = *reinterpret_cast<const int4*>(&col[p]);
            __half2 v0 = mp[(size_t)c.x * 64 + lane];
            __half2 v1 = mp[(size_t)c.y * 64 + lane];
            __half2 v2 = mp[(size_t)c.z * 64 + lane];
            __half2 v3 = mp[(size_t)c.w * 64 + lane];
            float2 f0 = __half22float2(v0), f1 = __half22float2(v1);
            float2 f2 = __half22float2(v2), f3 = __half22float2(v3);
            ax += f0.x; ay += f0.y; bx += f1.x; by += f1.y;
            ax += f2.x; ay += f2.y; bx += f3.x; by += f3.y;
        }
        for (; p < e; ++p) {
            float2 f = __half22float2(mp[(size_t)col[p] * 64 + lane]);
            ax += f.x; ay += f.y;
        }
        float2 fi = __half22float2(mp[(size_t)n * 64 + lane]);
        ax += fi.x; ay += fi.y;
        float di = dinv[n];
        float ox = fmaxf(fmaf(di, ax + bx, b2.x), 0.f);
        float oy = fmaxf(fmaf(di, ay + by, b2.y), 0.f);
        int c = lane >> 2, off = (lane * 2) & 7;
        *reinterpret_cast<__half2*>(&Hs[i * 128 + ((c ^ (i & 7)) << 3) + off]) =
            __floats2half2_rn(ox, oy);
    }

    // ---- phase 2: Hs[16][128] @ Wt^T -> C (same-wave, no barrier needed) --
    f32x4 acc[NP / 16] = {};
#pragma unroll
    for (int s = 0; s < 4; ++s) {
        int kc = s * 4 + (lane >> 4);
        int r = lane & 15;
        f16x8 af = *reinterpret_cast<const f16x8*>(&Hs[r * 128 + ((kc ^ (r & 7)) << 3)]);
#pragma unroll
        for (int nf = 0; nf < NP / 16; ++nf) {
            int n = nf * 16 + (lane & 15);
            f16x8 bf = *reinterpret_cast<const f16x8*>(&Wt[n * 128 + kc * 8]);
            acc[nf] = __builtin_amdgcn_mfma_f32_16x16x32_f16(af, bf, acc[nf], 0, 0, 0);
        }
    }
#pragma unroll
    for (int nf = 0; nf < NP / 16; ++nf) {
#pragma unroll
        for (int q = 0; q < 4; ++q) {
            int lr = (lane >> 4) * 4 + q;
            int grow = row0 + lr;
            int gcol = nf * 16 + (lane & 15);
            if (grow < N && (NP == NR || gcol < NR))
                C[(size_t)grow * NR + gcol] = (f16)(acc[nf][q] * dinv[grow]);
        }
    }
}

// ---------------- Final aggregation + log_softmax (R3) -------------------
__global__ __launch_bounds__(256) void agg_out_kernel(
        const __half* __restrict__ m, const int* __restrict__ col,
        const int* __restrict__ start,
        const float* __restrict__ dinv, const float* __restrict__ bias,
        float* __restrict__ out, int N) {
    int w = (int)((blockIdx.x * 256 + threadIdx.x) >> 6);
    int lane = threadIdx.x & 63;
    if (w >= N) return;
    bool act = lane < NCLASS;
    int cl = act ? lane : 0;
    int s = start[w];
    int e = start[w + 1];
    float a0 = 0.f, a1 = 0.f;
    int p = s;
    for (; p + 8 <= e; p += 8) {
        int j[8];
#pragma unroll
        for (int u = 0; u < 8; ++u) j[u] = col[p + u];
        __half v[8];
#pragma unroll
        for (int u = 0; u < 8; ++u) v[u] = m[(size_t)j[u] * NCLASS + cl];
#pragma unroll
        for (int u = 0; u < 8; ++u) {
            if (u & 1) a1 += __half2float(v[u]);
            else       a0 += __half2float(v[u]);
        }
    }
    for (; p < e; ++p) a0 += __half2float(m[(size_t)col[p] * NCLASS + cl]);
    a0 += __half2float(m[(size_t)w * NCLASS + cl]);
    float di = dinv[w];
    float h = fmaxf(fmaf(di, a0 + a1, bias[cl]), 0.f);
    float hm = act ? h : -INFINITY;
#pragma unroll
    for (int off = 32; off; off >>= 1) hm = fmaxf(hm, __shfl_xor(hm, off, 64));
    float ex = act ? expf(h - hm) : 0.f;
    float se = ex;
#pragma unroll
    for (int off = 32; off; off >>= 1) se += __shfl_xor(se, off, 64);
    if (act) out[(size_t)w * NCLASS + lane] = h - hm - logf(se);
}

// ------------------------------ launch -----------------------------------

extern "C" void kernel_launch(void* const* d_in, const int* in_sizes, int n_in,
                              void* d_out, int out_size, void* d_ws, size_t ws_size,
                              hipStream_t stream) {
    const float* x  = (const float*)d_in[0];
    const int*   ei = (const int*)d_in[1];
    const float* W0 = (const float*)d_in[2];
    const float* b0 = (const float*)d_in[3];
    const float* W1 = (const float*)d_in[4];
    const float* b1 = (const float*)d_in[5];
    const float* W2 = (const float*)d_in[6];
    const float* b2 = (const float*)d_in[7];
    float* out = (float*)d_out;

    const int NFEATr = 256;
    const int N = in_sizes[0] / NFEATr;  // 100000
    const int E = in_sizes[1] / 2;       // 1600000
    const int* src = ei;
    const int* dst = ei + E;

    const int nbuk = (N + 63) >> 6;      // 1563
    const int chunk = (E + NBLK - 1) / NBLK;

    char* p = (char*)d_ws;
    auto alloc = [&](size_t bytes) -> void* {
        void* r = (void*)p;
        p += (bytes + 255) & ~(size_t)255;
        return r;
    };
    int*    bh     = (int*)alloc((size_t)NBLK * nbuk * 4);
    int*    T      = (int*)alloc((size_t)nbuk * 4);
    int*    BB     = (int*)alloc((size_t)(nbuk + 1) * 4);
    int*    offb   = (int*)alloc((size_t)NBLK * nbuk * 4);
    int*    eb     = (int*)alloc((size_t)E * 4);
    int*    col    = (int*)alloc((size_t)E * 4);
    int*    startA = (int*)alloc((size_t)(N + 1) * 4);
    float*  dinv   = (float*)alloc((size_t)N * 4);
    f16*    Wt1    = (f16*)alloc((size_t)128 * 128 * 2);
    f16*    Wt2    = (f16*)alloc((size_t)48 * 128 * 2);
    f16*    mbuf   = (f16*)alloc((size_t)N * NHID * 2);   // m0, later m2 (40-wide)
    f16*    m1buf  = (f16*)alloc((size_t)N * NHID * 2);   // m1

    int nbl7 = (nbuk + 255) / 256;

    prep_w<<<88, 256, 0, stream>>>(W1, W2, Wt1, Wt2);
    bucket_hist<<<NBLK, 256, 0, stream>>>(dst, bh, E, nbuk, chunk);
    bucket_total<<<nbl7, 256, 0, stream>>>(bh, T, nbuk);
    bucket_scan<<<1, 256, 0, stream>>>(T, BB, nbuk, E);
    bucket_expand<<<nbl7, 256, 0, stream>>>(bh, BB, offb, nbuk);
    bucket_scatter<<<NBLK, 256, 0, stream>>>(src, dst, offb, eb, E, nbuk, chunk);
    bucket_csr<<<nbuk, 256, 0, stream>>>(eb, BB, startA, dinv, col, N, E);

    int g128 = (N + 127) / 128;
    int gfuse = (N + 15) / 16;
    int abl = (N + 3) / 4;

    // layer 0: x fp32 [N,256] @ W0 -> mbuf f16 (prescaled by dinv[row])
    gemm_mfma<256, 128, 128, 2, 2, false, false><<<g128, 256, 0, stream>>>(
        (const void*)x, W0, dinv, mbuf, N, NHID);

    // layer 0 agg + layer 1 gemm fused: mbuf -> m1buf (prescaled)
    agg_gemm<128, 128><<<gfuse, 64, 0, stream>>>((const __half*)mbuf, col, startA,
                                                 dinv, b0, Wt1, m1buf, N);

    // layer 1 agg + layer 2 gemm fused: m1buf -> mbuf (40-wide, prescaled)
    agg_gemm<48, NCLASS><<<gfuse, 64, 0, stream>>>((const __half*)m1buf, col, startA,
                                                   dinv, b1, Wt2, mbuf, N);

    // layer 2 agg + bias + relu + log_softmax
    agg_out_kernel<<<abl, 256, 0, stream>>>((const __half*)mbuf, col, startA, dinv, b2,
                                            out, N);
}